// Round 1
// baseline (895.961 us; speedup 1.0000x reference)
//
#include <hip/hip_runtime.h>

#define BATCH 4096
#define SEQ   2048
#define EMB   10
#define HID   50
#define VOCAB 14
#define TROW  2052     // token row stride bytes (u8): /4=513 ≡ 1 mod 32 -> conflict-free

using bf16x8 = __attribute__((ext_vector_type(8))) short;
using f32x4  = __attribute__((ext_vector_type(4))) float;

__device__ __forceinline__ short f2bf(float f) {
  unsigned u = __builtin_bit_cast(unsigned, f);
  u = (u + 0x7FFFu + ((u >> 16) & 1u)) >> 16;   // round-to-nearest-even
  return (short)u;
}
__device__ __forceinline__ float fsigm(float x) {
  return __builtin_amdgcn_rcpf(1.0f + __builtin_amdgcn_exp2f(x * -1.44269504f));
}
// HW packed f32->bf16 (RNE), 1 instr instead of ~8-op software RNE pack.
__device__ __forceinline__ unsigned cvtpk(float lo, float hi) {
  unsigned r;
  asm("v_cvt_pk_bf16_f32 %0, %1, %2" : "=v"(r) : "v"(lo), "v"(hi));
  return r;
}

// ---------------------------------------------------------------------------
// Pack A fragments (bf16, pre-scaled) for mfma_f32_16x16x32_bf16.
// 13 flat tiles. Tile tid, row m: q=m>>2 (dest quad), g=m&3 (gate).
//   tid<10  (fat pairs)  : jh = 2*((tid>>1)*4 + q) + (tid&1)   -> jh 0..39
//   tid>=10 (singles)    : jh = 40 + (tid-10)*4 + q            -> jh 40..51 (50,51 pad)
// i/f/o rows scaled by -log2e, g rows by -2log2e (fused-fraction epilogue).
//   k < 50 : W_hh[R][k]*scale ; k >= 50 : gxi[v=k-50][R]*scale,  R = g*50+jh
// UNCHANGED from the 811us version.
// ---------------------------------------------------------------------------
__global__ void prep_kernel(const float* __restrict__ emb,  const float* __restrict__ W_ih,
                            const float* __restrict__ W_hh, const float* __restrict__ b_ih,
                            const float* __restrict__ b_hh, short* __restrict__ Apack) {
  int idx = blockIdx.x * 256 + threadIdx.x;       // total 13*2*64*8 = 13312
  if (idx >= 13 * 2 * 64 * 8) return;
  int j    = idx & 7;
  int lane = (idx >> 3) & 63;
  int kf   = (idx >> 9) & 1;
  int tid  = idx >> 10;                            // tile 0..12
  int m    = lane & 15;
  int q    = m >> 2, g = m & 3;
  int jh   = (tid < 10) ? (2 * ((tid >> 1) * 4 + q) + (tid & 1))
                        : (40 + (tid - 10) * 4 + q);
  int k    = kf * 32 + (lane >> 4) * 8 + j;
  float v = 0.0f;
  if (jh < HID) {
    int R = g * HID + jh;
    float scale = (g == 2) ? -2.885390082f : -1.442695041f;
    if (k < HID) {
      v = W_hh[R * HID + k] * scale;
    } else {
      int vo = k - HID;                            // vocab id 0..13
      float s = b_ih[R] + b_hh[R];
      for (int e = 0; e < EMB; ++e) s += emb[vo * EMB + e] * W_ih[R * EMB + e];
      v = s * scale;
    }
  }
  Apack[idx] = f2bf(v);
}

// fused-fraction LSTM cell pair: 10 exp2 + 2 shared rcp
__device__ __forceinline__ void cell_pair(f32x4 A, f32x4 B, bool keep,
                                          float& c0r, float& h0r, float& c1r, float& h1r) {
  float eA0 = __builtin_amdgcn_exp2f(A[0]);
  float eB0 = __builtin_amdgcn_exp2f(A[1]);
  float eC0 = __builtin_amdgcn_exp2f(A[2]);
  float eG0 = __builtin_amdgcn_exp2f(A[3]);
  float eA1 = __builtin_amdgcn_exp2f(B[0]);
  float eB1 = __builtin_amdgcn_exp2f(B[1]);
  float eC1 = __builtin_amdgcn_exp2f(B[2]);
  float eG1 = __builtin_amdgcn_exp2f(B[3]);
  float a10 = 1.f + eA0, b10 = 1.f + eB0, c10 = 1.f + eC0, g10 = 1.f + eG0;
  float a11 = 1.f + eA1, b11 = 1.f + eB1, c11 = 1.f + eC1, g11 = 1.f + eG1;
  float P0 = a10 * c10, P1 = a11 * c11;
  float t10 = __builtin_fmaf(-eC0, b10, b10);
  float t11 = __builtin_fmaf(-eC1, b11, b11);
  float num0 = __builtin_fmaf(c0r, P0, t10);
  float num1 = __builtin_fmaf(c1r, P1, t11);
  float den0 = P0 * b10, den1 = P1 * b11;
  float r  = __builtin_amdgcn_rcpf(den0 * den1);
  float cn0 = num0 * (den1 * r);
  float cn1 = num1 * (den0 * r);
  float cl0 = fminf(cn0 * -2.885390082f, 40.0f);
  float cl1 = fminf(cn1 * -2.885390082f, 40.0f);
  float H0 = __builtin_amdgcn_exp2f(cl0);
  float H1 = __builtin_amdgcn_exp2f(cl1);
  float hd0 = g10 * (1.f + H0);
  float hd1 = g11 * (1.f + H1);
  float rh = __builtin_amdgcn_rcpf(hd0 * hd1);
  float hn0 = (1.f - H0) * (hd1 * rh);
  float hn1 = (1.f - H1) * (hd0 * rh);
  c0r = keep ? cn0 : c0r;  h0r = keep ? hn0 : h0r;
  c1r = keep ? cn1 : c1r;  h1r = keep ? hn1 : h1r;
}

// single cell: 5 exp2 + 2 rcp
__device__ __forceinline__ void cell_single(f32x4 A, bool keep, float& cr, float& hr) {
  float eA = __builtin_amdgcn_exp2f(A[0]);
  float eB = __builtin_amdgcn_exp2f(A[1]);
  float eC = __builtin_amdgcn_exp2f(A[2]);
  float eG = __builtin_amdgcn_exp2f(A[3]);
  float a1 = 1.f + eA, bb1 = 1.f + eB, cc1 = 1.f + eC, g1 = 1.f + eG;
  float P   = a1 * cc1;
  float t1  = __builtin_fmaf(-eC, bb1, bb1);
  float num = __builtin_fmaf(cr, P, t1);
  float den = P * bb1;
  float cn  = num * __builtin_amdgcn_rcpf(den);
  float cl  = fminf(cn * -2.885390082f, 40.0f);
  float eH  = __builtin_amdgcn_exp2f(cl);
  float hd  = g1 * (1.f + eH);
  float hn  = (1.f - eH) * __builtin_amdgcn_rcpf(hd);
  cr = keep ? cn : cr;
  hr = keep ? hn : hr;
}

#define HWB32(p) (bB * 128 + 16 * ((((p) >> 2) + bB) & 7) + ((4 * (p)) & 15))
#define HWB16(j) (bB * 128 + 16 * ((((j) >> 3) + bB) & 7) + 2 * ((j) & 7))

// ---------------------------------------------------------------------------
// Main: 256 wgs x 256 threads (4 waves), one wg owns 16 batch rows.
// R11 theory: the old 8-wave layout put 2 LOCKSTEP waves per SIMD — released
// by the same barrier, stalling at the same points, so the 2nd wave hid no
// latency but doubled the per-step B-fragment LDS broadcast (16KB -> 8KB) and
// widened the barrier. Max-SIMD issue load is unchanged (4 cells/step: old
// SIMD1 carried fat waves {1,5}; new w0/w1 carry 2 fat pairs each) and each
// wave now holds 4 independent cell chains for in-wave latency hiding.
// Roles: w0 = tiles 0..3 (fat pairs 0,1), w1 = tiles 4..7 (fat pairs 2,3),
// w2 = tiles 8,9 (fat pair 4) + single tile 10, w3 = singles 11,12
// (cross-paired for shared rcp) + BOTH one-hot duties (2 words/lane).
// h pack now via v_cvt_pk_bf16_f32 (1 instr, RNE — bit-identical to f2bf).
// ---------------------------------------------------------------------------
__global__ __launch_bounds__(256, 1) void lstm_kernel(
    const int* __restrict__ tokens, const short* __restrict__ Apack,
    const float* __restrict__ W1, const float* __restrict__ b1,
    const float* __restrict__ W2, const float* __restrict__ b2,
    float* __restrict__ out) {
  __shared__ __align__(16) unsigned char toku8[16 * TROW];   // 32832 B
  __shared__ __align__(16) short hbuf[2][16 * 64];           // 4096 B, swizzled
  __shared__ float hfin[16 * 52];
  __shared__ float mlp_hid[16 * 52];

  const int tid  = threadIdx.x;
  const int lane = tid & 63;
  const int wv   = tid >> 6;           // 0..3
  const int b0   = blockIdx.x * 16;
  const int bB   = lane & 15;          // batch col (B-frag & C col)
  const int jj   = lane >> 4;          // quad

  // ---- persistent A fragments (contiguous tile runs per wave)
  bf16x8 A0{}, A1{}, A2{}, A3{}, A4{}, A5{}, A6{}, A7{};
  {
    int base  = (wv == 0) ? 0 : (wv == 1) ? 4 : (wv == 2) ? 8 : 11;
    int ntile = (wv <= 1) ? 4 : (wv == 2) ? 3 : 2;
    const short* ap = Apack + (base * 128 + lane) * 8;
    A0 = *(const bf16x8*)(ap + 0 * 512);
    A1 = *(const bf16x8*)(ap + 1 * 512);
    A2 = *(const bf16x8*)(ap + 2 * 512);
    A3 = *(const bf16x8*)(ap + 3 * 512);
    if (ntile >= 3) { A4 = *(const bf16x8*)(ap + 4 * 512);
                      A5 = *(const bf16x8*)(ap + 5 * 512); }
    if (ntile == 4) { A6 = *(const bf16x8*)(ap + 6 * 512);
                      A7 = *(const bf16x8*)(ap + 7 * 512); }
  }

  // ---- loop-invariant LDS byte offsets (XOR-swizzled 128 B rows)
  char* hb = (char*)hbuf;
  const int rb0 = bB * 128 + 16 * ((jj + bB) & 7);          // B octet jj
  const int rb1 = bB * 128 + 16 * (((jj + 4) + bB) & 7);    // B octet jj+4
  int hw0, hw1 = 0;
  bool w1valid = true;
  if (wv == 0)      { hw0 = HWB32(jj);       hw1 = HWB32(4 + jj); }
  else if (wv == 1) { hw0 = HWB32(8 + jj);   hw1 = HWB32(12 + jj); }
  else if (wv == 2) { hw0 = HWB32(16 + jj);  hw1 = HWB16(40 + jj); }
  else              { hw0 = HWB16(44 + jj);  hw1 = HWB16(48 + jj);
                      w1valid = (jj < 2); }

  // ---- one-hot duty: wave 3 only, 2 words/lane (rows r and r+8)
  const bool ohact = (wv == 3) && (lane < 56);
  const int ohr0  = lane / 7;                  // batch row 0..7
  const int ohsub = lane % 7;                  // word covering vocab 2w,2w+1
  const int ohoct = (ohsub < 3) ? 6 : 7;
  const int ohinn = (ohsub < 3) ? (4 + 4 * ohsub) : (4 * (ohsub - 3));
  const int ohr1  = ohr0 + 8;
  const int ohb0  = ohr0 * 128 + 16 * ((ohoct + ohr0) & 7) + ohinn;
  const int ohb1  = ohr1 * 128 + 16 * ((ohoct + ohr1) & 7) + ohinn;
  const int ohv0  = 2 * ohsub, ohv1 = 2 * ohsub + 1;
  const unsigned char* oht0 = &toku8[ohr0 * TROW];
  const unsigned char* oht1 = &toku8[ohr1 * TROW];
  const unsigned char* myrow = &toku8[bB * TROW];    // keep-mask tokens

  // ---- stage tokens (int32 -> u8) and zero hbuf[0]
  for (int i = tid; i < 16 * 512; i += 256) {          // 8192 int4-groups
    int row = i >> 9, c4 = i & 511;
    int4 tv = *(const int4*)&tokens[(b0 + row) * SEQ + 4 * c4];
    unsigned pk = (tv.x & 0xFF) | ((tv.y & 0xFF) << 8) |
                  ((tv.z & 0xFF) << 16) | ((tv.w & 0xFF) << 24);
    *(unsigned*)&toku8[row * TROW + 4 * c4] = pk;
  }
  for (int i = tid; i < 1024; i += 256) hbuf[0][i] = 0;
  __syncthreads();

  // one-hot for t=0
  if (ohact) {
    int tk0 = oht0[0], tk1 = oht1[0];
    *(unsigned*)(hb + ohb0) = ((tk0 == ohv0) ? 0x3F80u : 0u) |
                              ((tk0 == ohv1) ? 0x3F800000u : 0u);
    *(unsigned*)(hb + ohb1) = ((tk1 == ohv0) ? 0x3F80u : 0u) |
                              ((tk1 == ohv1) ? 0x3F800000u : 0u);
  }

  float sc0 = 0.f, sh0 = 0.f, sc1 = 0.f, sh1 = 0.f;
  float sc2 = 0.f, sh2 = 0.f, sc3 = 0.f, sh3 = 0.f;
  unsigned mp = 0;

  for (int t = 0; t < SEQ; t += 4) {
#pragma unroll
    for (int u = 0; u < 4; ++u) {
      const int T  = t + u;
      const int PB = (u & 1) * 2048, PN = PB ^ 2048;
      __syncthreads();   // hbuf[PB] ready; LDS-only -> lgkmcnt drain

      bf16x8 Bf0 = *(const bf16x8*)(hb + PB + rb0);
      bf16x8 Bf1 = *(const bf16x8*)(hb + PB + rb1);
      if (u == 0) mp = *(const unsigned*)(myrow + T);   // tokens T..T+3

      // fill the ds_read shadow: one-hot for step T+1 into hbuf[PN]
      if (ohact && T + 1 < SEQ) {
        int tk0 = oht0[T + 1], tk1 = oht1[T + 1];
        *(unsigned*)(hb + PN + ohb0) = ((tk0 == ohv0) ? 0x3F80u : 0u) |
                                       ((tk0 == ohv1) ? 0x3F800000u : 0u);
        *(unsigned*)(hb + PN + ohb1) = ((tk1 == ohv0) ? 0x3F80u : 0u) |
                                       ((tk1 == ohv1) ? 0x3F800000u : 0u);
      }

      const bool keep = (((mp >> (8 * u)) & 0xFFu) != 0u);
      const f32x4 z = {0.f, 0.f, 0.f, 0.f};

      if (wv <= 1) {
        f32x4 a0 = z, a1 = z, a2 = z, a3 = z;
        a0 = __builtin_amdgcn_mfma_f32_16x16x32_bf16(A0, Bf0, a0, 0, 0, 0);
        a0 = __builtin_amdgcn_mfma_f32_16x16x32_bf16(A1, Bf1, a0, 0, 0, 0);
        a1 = __builtin_amdgcn_mfma_f32_16x16x32_bf16(A2, Bf0, a1, 0, 0, 0);
        a1 = __builtin_amdgcn_mfma_f32_16x16x32_bf16(A3, Bf1, a1, 0, 0, 0);
        a2 = __builtin_amdgcn_mfma_f32_16x16x32_bf16(A4, Bf0, a2, 0, 0, 0);
        a2 = __builtin_amdgcn_mfma_f32_16x16x32_bf16(A5, Bf1, a2, 0, 0, 0);
        a3 = __builtin_amdgcn_mfma_f32_16x16x32_bf16(A6, Bf0, a3, 0, 0, 0);
        a3 = __builtin_amdgcn_mfma_f32_16x16x32_bf16(A7, Bf1, a3, 0, 0, 0);
        cell_pair(a0, a1, keep, sc0, sh0, sc1, sh1);
        cell_pair(a2, a3, keep, sc2, sh2, sc3, sh3);
        *(unsigned*)(hb + PN + hw0) = cvtpk(sh0, sh1);
        *(unsigned*)(hb + PN + hw1) = cvtpk(sh2, sh3);
      } else if (wv == 2) {
        f32x4 a0 = z, a1 = z, a2 = z;
        a0 = __builtin_amdgcn_mfma_f32_16x16x32_bf16(A0, Bf0, a0, 0, 0, 0);
        a0 = __builtin_amdgcn_mfma_f32_16x16x32_bf16(A1, Bf1, a0, 0, 0, 0);
        a1 = __builtin_amdgcn_mfma_f32_16x16x32_bf16(A2, Bf0, a1, 0, 0, 0);
        a1 = __builtin_amdgcn_mfma_f32_16x16x32_bf16(A3, Bf1, a1, 0, 0, 0);
        a2 = __builtin_amdgcn_mfma_f32_16x16x32_bf16(A4, Bf0, a2, 0, 0, 0);
        a2 = __builtin_amdgcn_mfma_f32_16x16x32_bf16(A5, Bf1, a2, 0, 0, 0);
        cell_pair(a0, a1, keep, sc0, sh0, sc1, sh1);
        cell_single(a2, keep, sc2, sh2);
        *(unsigned*)(hb + PN + hw0) = cvtpk(sh0, sh1);
        *(short*)(hb + PN + hw1) = (short)cvtpk(sh2, sh2);
      } else {
        f32x4 a0 = z, a1 = z;
        a0 = __builtin_amdgcn_mfma_f32_16x16x32_bf16(A0, Bf0, a0, 0, 0, 0);
        a0 = __builtin_amdgcn_mfma_f32_16x16x32_bf16(A1, Bf1, a0, 0, 0, 0);
        a1 = __builtin_amdgcn_mfma_f32_16x16x32_bf16(A2, Bf0, a1, 0, 0, 0);
        a1 = __builtin_amdgcn_mfma_f32_16x16x32_bf16(A3, Bf1, a1, 0, 0, 0);
        cell_pair(a0, a1, keep, sc0, sh0, sc1, sh1);
        unsigned pk = cvtpk(sh0, sh1);
        *(short*)(hb + PN + hw0) = (short)pk;
        if (w1valid) *(short*)(hb + PN + hw1) = (short)(pk >> 16);
      }
    }
  }

  // ---- final h -> MLP -> sigmoid
  if (wv <= 1) {
    const int p0 = (wv == 0) ? jj : (8 + jj);
    const int p1 = p0 + 4;
    hfin[bB * 52 + 2 * p0]     = sh0;
    hfin[bB * 52 + 2 * p0 + 1] = sh1;
    hfin[bB * 52 + 2 * p1]     = sh2;
    hfin[bB * 52 + 2 * p1 + 1] = sh3;
  } else if (wv == 2) {
    hfin[bB * 52 + 32 + 2 * jj] = sh0;
    hfin[bB * 52 + 33 + 2 * jj] = sh1;
    hfin[bB * 52 + 40 + jj]     = sh2;
  } else {
    hfin[bB * 52 + 44 + jj] = sh0;
    if (jj < 2) hfin[bB * 52 + 48 + jj] = sh1;
  }
  __syncthreads();
  for (int idx = tid; idx < 16 * 64; idx += 256) {
    int b = idx >> 6, m = idx & 63;
    if (m < HID) {
      float s = b1[m];
      for (int j2 = 0; j2 < HID; ++j2) s += hfin[b * 52 + j2] * W1[m * HID + j2];
      mlp_hid[b * 52 + m] = s;
    }
  }
  __syncthreads();
  if (tid < 16) {
    float s = b2[0];
    for (int m2 = 0; m2 < HID; ++m2) s += mlp_hid[tid * 52 + m2] * W2[m2];
    out[b0 + tid] = fsigm(s);
  }
}

extern "C" void kernel_launch(void* const* d_in, const int* in_sizes, int n_in,
                              void* d_out, int out_size, void* d_ws, size_t ws_size,
                              hipStream_t stream) {
  const int*   tokens = (const int*)  d_in[0];
  const float* emb    = (const float*)d_in[1];
  const float* W_ih   = (const float*)d_in[2];
  const float* W_hh   = (const float*)d_in[3];
  const float* b_ih   = (const float*)d_in[4];
  const float* b_hh   = (const float*)d_in[5];
  const float* W1     = (const float*)d_in[6];
  const float* b1     = (const float*)d_in[7];
  const float* W2     = (const float*)d_in[8];
  const float* b2     = (const float*)d_in[9];
  float* outp  = (float*)d_out;
  short* Apack = (short*)d_ws;                 // 13312 bf16 = 26.6 KB

  hipLaunchKernelGGL(prep_kernel, dim3(52), dim3(256), 0, stream,
                     emb, W_ih, W_hh, b_ih, b_hh, Apack);
  hipLaunchKernelGGL(lstm_kernel, dim3(BATCH / 16), dim3(256), 0, stream,
                     tokens, Apack, W1, b1, W2, b2, outp);
}

// Round 2
// 838.663 us; speedup vs baseline: 1.0683x; 1.0683x over previous
//
#include <hip/hip_runtime.h>

#define BATCH 4096
#define SEQ   2048
#define EMB   10
#define HID   50
#define VOCAB 14
#define TROW  2052     // token row stride bytes (u8): /4=513 ≡ 1 mod 32 -> conflict-free

using bf16x8 = __attribute__((ext_vector_type(8))) short;
using f32x4  = __attribute__((ext_vector_type(4))) float;

__device__ __forceinline__ short f2bf(float f) {
  unsigned u = __builtin_bit_cast(unsigned, f);
  u = (u + 0x7FFFu + ((u >> 16) & 1u)) >> 16;   // round-to-nearest-even
  return (short)u;
}
__device__ __forceinline__ float fsigm(float x) {
  return __builtin_amdgcn_rcpf(1.0f + __builtin_amdgcn_exp2f(x * -1.44269504f));
}
// HW packed f32->bf16 (RNE), 1 instr; low 16 bits = bf16(lo).
__device__ __forceinline__ unsigned cvtpk(float lo, float hi) {
  unsigned r;
  asm("v_cvt_pk_bf16_f32 %0, %1, %2" : "=v"(r) : "v"(lo), "v"(hi));
  return r;
}

// ---------------------------------------------------------------------------
// Pack A fragments (bf16, pre-scaled) for mfma_f32_16x16x32_bf16.
// 13 flat tiles. Tile tid, row m: q=m>>2 (dest quad), g=m&3 (gate).
//   tid<10  (fat pairs)  : jh = 2*((tid>>1)*4 + q) + (tid&1)   -> jh 0..39
//   tid>=10 (singles)    : jh = 40 + (tid-10)*4 + q            -> jh 40..51 (50,51 pad)
// i/f/o rows scaled by -log2e, g rows by -2log2e (fused-fraction epilogue).
//   k < 50 : W_hh[R][k]*scale ; k >= 50 : gxi[v=k-50][R]*scale,  R = g*50+jh
// UNCHANGED from the 811us version.
// ---------------------------------------------------------------------------
__global__ void prep_kernel(const float* __restrict__ emb,  const float* __restrict__ W_ih,
                            const float* __restrict__ W_hh, const float* __restrict__ b_ih,
                            const float* __restrict__ b_hh, short* __restrict__ Apack) {
  int idx = blockIdx.x * 256 + threadIdx.x;       // total 13*2*64*8 = 13312
  if (idx >= 13 * 2 * 64 * 8) return;
  int j    = idx & 7;
  int lane = (idx >> 3) & 63;
  int kf   = (idx >> 9) & 1;
  int tid  = idx >> 10;                            // tile 0..12
  int m    = lane & 15;
  int q    = m >> 2, g = m & 3;
  int jh   = (tid < 10) ? (2 * ((tid >> 1) * 4 + q) + (tid & 1))
                        : (40 + (tid - 10) * 4 + q);
  int k    = kf * 32 + (lane >> 4) * 8 + j;
  float v = 0.0f;
  if (jh < HID) {
    int R = g * HID + jh;
    float scale = (g == 2) ? -2.885390082f : -1.442695041f;
    if (k < HID) {
      v = W_hh[R * HID + k] * scale;
    } else {
      int vo = k - HID;                            // vocab id 0..13
      float s = b_ih[R] + b_hh[R];
      for (int e = 0; e < EMB; ++e) s += emb[vo * EMB + e] * W_ih[R * EMB + e];
      v = s * scale;
    }
  }
  Apack[idx] = f2bf(v);
}

#define HWB16(j) (bB * 128 + 16 * ((((j) >> 3) + bB) & 7) + 2 * ((j) & 7))

// ---------------------------------------------------------------------------
// Main: 256 wgs x 832 threads (13 waves), one wg owns 16 batch rows.
// R12 theory (post-mortem of R11): per-step period = max over waves of the
// post-barrier serial chain. R11 (4 waves x 4 tiles) lengthened the chain and
// regressed; R8 (8 waves, <=2 tiles) was better. So go the other way: 13
// waves x exactly 1 tile. Each lane owns ONE cell -> shortest possible
// epilogue chain (cell_single, 5 exp2 + 2 uncoupled rcp), and each SIMD hosts
// 3-4 INDEPENDENT short chains that interleave to fill dep stalls.
// Max waves/SIMD = 4 under round-robin {4,3,3,3} or block {4,4,4,1} mapping.
// MFMA count/step unchanged (26). One-hot duty on waves 10,11 (singles,
// short chain). h-store via v_cvt_pk_bf16_f32 (1 instr, RNE == f2bf).
// ---------------------------------------------------------------------------
__global__ __launch_bounds__(832, 1) void lstm_kernel(
    const int* __restrict__ tokens, const short* __restrict__ Apack,
    const float* __restrict__ W1, const float* __restrict__ b1,
    const float* __restrict__ W2, const float* __restrict__ b2,
    float* __restrict__ out) {
  __shared__ __align__(16) unsigned char toku8[16 * TROW];   // 32832 B
  __shared__ __align__(16) short hbuf[2][16 * 64];           // 4096 B, swizzled
  __shared__ float hfin[16 * 52];
  __shared__ float mlp_hid[16 * 52];

  const int tid  = threadIdx.x;
  const int lane = tid & 63;
  const int wv   = tid >> 6;           // 0..12 == tile id
  const int b0   = blockIdx.x * 16;
  const int bB   = lane & 15;          // batch col (B-frag & C col)
  const int jj   = lane >> 4;          // quad

  // ---- per-lane cell id (tile wv, quad jj)
  const int jh = (wv < 10) ? (2 * ((wv >> 1) * 4 + jj) + (wv & 1))
                           : (40 + (wv - 10) * 4 + jj);
  const bool hval = (jh < HID);

  // ---- persistent A fragments (1 tile = 2 K-halves)
  const bf16x8 Af0 = *(const bf16x8*)(Apack + ((wv * 2 + 0) * 64 + lane) * 8);
  const bf16x8 Af1 = *(const bf16x8*)(Apack + ((wv * 2 + 1) * 64 + lane) * 8);

  // ---- loop-invariant LDS byte offsets (XOR-swizzled 128 B rows)
  char* hb = (char*)hbuf;
  const int rb0 = bB * 128 + 16 * ((jj + bB) & 7);          // B octet jj (k 0..31)
  const int rb1 = bB * 128 + 16 * (((jj + 4) + bB) & 7);    // B octet jj+4 (k 32..63)
  const int hw  = HWB16(jh);                                 // own h slot

  // ---- one-hot duty: waves 10,11, 56 lanes each (8 rows x 7 words)
  const bool ohact = (wv == 10 || wv == 11) && (lane < 56);
  const int ohr   = (wv - 10) * 8 + lane / 7;   // batch row 0..15
  const int ohsub = lane % 7;                    // word covering vocab 2w,2w+1
  const int ohoct = (ohsub < 3) ? 6 : 7;
  const int ohinn = (ohsub < 3) ? (4 + 4 * ohsub) : (4 * (ohsub - 3));
  const int ohb   = ohr * 128 + 16 * ((ohoct + ohr) & 7) + ohinn;
  const int ohv0  = 2 * ohsub, ohv1 = 2 * ohsub + 1;
  const unsigned char* ohtok = &toku8[ohr * TROW];
  const unsigned char* myrow = &toku8[bB * TROW];    // keep-mask tokens

  // ---- stage tokens (int32 -> u8) and zero hbuf[0]
  for (int i = tid; i < 16 * 512; i += 832) {          // 8192 int4-groups
    int row = i >> 9, c4 = i & 511;
    int4 tv = *(const int4*)&tokens[(b0 + row) * SEQ + 4 * c4];
    unsigned pk = (tv.x & 0xFF) | ((tv.y & 0xFF) << 8) |
                  ((tv.z & 0xFF) << 16) | ((tv.w & 0xFF) << 24);
    *(unsigned*)&toku8[row * TROW + 4 * c4] = pk;
  }
  for (int i = tid; i < 1024; i += 832) hbuf[0][i] = 0;
  __syncthreads();

  // one-hot for t=0 (into buffer 0; ordered before first loop barrier)
  if (ohact) {
    int tk = ohtok[0];
    *(unsigned*)(hb + ohb) = ((tk == ohv0) ? 0x3F80u : 0u) |
                             ((tk == ohv1) ? 0x3F800000u : 0u);
  }

  float sc = 0.f, sh = 0.f;
  unsigned mp = 0;

  for (int t = 0; t < SEQ; t += 4) {
#pragma unroll
    for (int u = 0; u < 4; ++u) {
      const int T  = t + u;
      const int PB = (u & 1) * 2048, PN = PB ^ 2048;
      __syncthreads();   // hbuf[PB] ready; LDS-only -> lgkmcnt drain

      bf16x8 Bf0 = *(const bf16x8*)(hb + PB + rb0);
      bf16x8 Bf1 = *(const bf16x8*)(hb + PB + rb1);
      if (u == 0) mp = *(const unsigned*)(myrow + T);   // tokens T..T+3

      // fill the ds_read shadow: one-hot for step T+1 into hbuf[PN]
      if (ohact && T + 1 < SEQ) {
        int tk = ohtok[T + 1];
        *(unsigned*)(hb + PN + ohb) = ((tk == ohv0) ? 0x3F80u : 0u) |
                                      ((tk == ohv1) ? 0x3F800000u : 0u);
      }

      const bool keep = (((mp >> (8 * u)) & 0xFFu) != 0u);

      f32x4 a = {0.f, 0.f, 0.f, 0.f};
      a = __builtin_amdgcn_mfma_f32_16x16x32_bf16(Af0, Bf0, a, 0, 0, 0);
      a = __builtin_amdgcn_mfma_f32_16x16x32_bf16(Af1, Bf1, a, 0, 0, 0);

      // single-cell fused-fraction epilogue: 5 exp2 + 2 rcp, short chain
      float eA = __builtin_amdgcn_exp2f(a[0]);
      float eB = __builtin_amdgcn_exp2f(a[1]);
      float eC = __builtin_amdgcn_exp2f(a[2]);
      float eG = __builtin_amdgcn_exp2f(a[3]);
      float a1 = 1.f + eA, bb1 = 1.f + eB, cc1 = 1.f + eC, g1 = 1.f + eG;
      float P   = a1 * cc1;
      float t1  = __builtin_fmaf(-eC, bb1, bb1);
      float num = __builtin_fmaf(sc, P, t1);
      float den = P * bb1;
      float cn  = num * __builtin_amdgcn_rcpf(den);
      float cl  = fminf(cn * -2.885390082f, 40.0f);
      float eH  = __builtin_amdgcn_exp2f(cl);
      float hd  = g1 * (1.f + eH);
      float hn  = (1.f - eH) * __builtin_amdgcn_rcpf(hd);
      sc = keep ? cn : sc;
      sh = keep ? hn : sh;
      if (hval) *(short*)(hb + PN + hw) = (short)cvtpk(sh, sh);
    }
  }

  // ---- final h -> MLP -> sigmoid
  if (hval) hfin[bB * 52 + jh] = sh;
  __syncthreads();
  for (int idx = tid; idx < 16 * 64; idx += 832) {
    int b = idx >> 6, m = idx & 63;
    if (m < HID) {
      float s = b1[m];
      for (int j2 = 0; j2 < HID; ++j2) s += hfin[b * 52 + j2] * W1[m * HID + j2];
      mlp_hid[b * 52 + m] = s;
    }
  }
  __syncthreads();
  if (tid < 16) {
    float s = b2[0];
    for (int m2 = 0; m2 < HID; ++m2) s += mlp_hid[tid * 52 + m2] * W2[m2];
    out[b0 + tid] = fsigm(s);
  }
}

extern "C" void kernel_launch(void* const* d_in, const int* in_sizes, int n_in,
                              void* d_out, int out_size, void* d_ws, size_t ws_size,
                              hipStream_t stream) {
  const int*   tokens = (const int*)  d_in[0];
  const float* emb    = (const float*)d_in[1];
  const float* W_ih   = (const float*)d_in[2];
  const float* W_hh   = (const float*)d_in[3];
  const float* b_ih   = (const float*)d_in[4];
  const float* b_hh   = (const float*)d_in[5];
  const float* W1     = (const float*)d_in[6];
  const float* b1     = (const float*)d_in[7];
  const float* W2     = (const float*)d_in[8];
  const float* b2     = (const float*)d_in[9];
  float* outp  = (float*)d_out;
  short* Apack = (short*)d_ws;                 // 13312 bf16 = 26.6 KB

  hipLaunchKernelGGL(prep_kernel, dim3(52), dim3(256), 0, stream,
                     emb, W_ih, W_hh, b_ih, b_hh, Apack);
  hipLaunchKernelGGL(lstm_kernel, dim3(BATCH / 16), dim3(832), 0, stream,
                     tokens, Apack, W1, b1, W2, b2, outp);
}